// Round 2
// baseline (2041.177 us; speedup 1.0000x reference)
//
#include <hip/hip_runtime.h>

#define TT 2048
#define BB 64

typedef float v2f __attribute__((ext_vector_type(2)));

__device__ __forceinline__ float frcp(float x) { return __builtin_amdgcn_rcpf(x); }
__device__ __forceinline__ float fsig(float x) { return frcp(1.f + __expf(-x)); }
__device__ __forceinline__ float ftan(float x) { return 1.f - 2.f * frcp(1.f + __expf(2.f * x)); }
__device__ __forceinline__ v2f fma2(v2f a, v2f b, v2f c) { return __builtin_elementwise_fma(a, b, c); }

// G[(b*Tc+tt)*256 + g] = sum_k X[b, t0+tt, k] * W_ih[g, k] + b_ih[g] + b_hh[g]
// Tiled fp32 GEMM: M = 64*Tc (rows b*Tc+tt), N = 256 (gates), K = 256.
// grid = (Tc, 4), block = 256. Tile 64x64, BK=32.
__global__ __launch_bounds__(256) void gates_gemm(const float* __restrict__ X,
                                                  const float* __restrict__ W,
                                                  const float* __restrict__ bih,
                                                  const float* __restrict__ bhh,
                                                  float* __restrict__ G,
                                                  int t0, int Tc) {
  __shared__ __align__(16) float As[32][64];  // As[k][m]
  __shared__ __align__(16) float Bs[32][64];  // Bs[k][n]
  const int tid = threadIdx.x;
  const int m0 = blockIdx.x * 64;   // chunk-row base; Tc%64==0 so tile stays in one b
  const int n0 = blockIdx.y * 64;
  const int bb = m0 / Tc;
  const int tt0 = m0 - bb * Tc;
  const int tx = tid & 15, ty = tid >> 4;
  const int r  = tid >> 2;          // 0..63 (row within tile)
  const int kq = (tid & 3) * 8;     // 0,8,16,24 (k-octet)
  const float* xrow = X + ((size_t)(bb * TT + t0 + tt0 + r)) * 256 + kq;
  const float* wrow = W + (size_t)(n0 + r) * 257 + kq;
  float acc[4][4] = {};
  for (int k0 = 0; k0 < 256; k0 += 32) {
    float4 a0 = *reinterpret_cast<const float4*>(xrow + k0);
    float4 a1 = *reinterpret_cast<const float4*>(xrow + k0 + 4);
    float bv[8];
#pragma unroll
    for (int u = 0; u < 8; ++u) bv[u] = wrow[k0 + u];
    if (k0 != 0) __syncthreads();   // prior compute done before overwriting LDS
    As[kq+0][r]=a0.x; As[kq+1][r]=a0.y; As[kq+2][r]=a0.z; As[kq+3][r]=a0.w;
    As[kq+4][r]=a1.x; As[kq+5][r]=a1.y; As[kq+6][r]=a1.z; As[kq+7][r]=a1.w;
#pragma unroll
    for (int u = 0; u < 8; ++u) Bs[kq+u][r] = bv[u];
    __syncthreads();
#pragma unroll
    for (int kk = 0; kk < 32; ++kk) {
      float4 av = *reinterpret_cast<const float4*>(&As[kk][ty*4]);
      float4 bw = *reinterpret_cast<const float4*>(&Bs[kk][tx*4]);
      const float aa[4] = {av.x, av.y, av.z, av.w};
      const float bbv[4] = {bw.x, bw.y, bw.z, bw.w};
#pragma unroll
      for (int i = 0; i < 4; ++i)
#pragma unroll
        for (int j = 0; j < 4; ++j) acc[i][j] += aa[i] * bbv[j];
    }
  }
  const int col = n0 + tx * 4;
  float bsum[4];
#pragma unroll
  for (int j = 0; j < 4; ++j) bsum[j] = bih[col + j] + bhh[col + j];
#pragma unroll
  for (int i = 0; i < 4; ++i) {
    float4 o;
    o.x = acc[i][0] + bsum[0];
    o.y = acc[i][1] + bsum[1];
    o.z = acc[i][2] + bsum[2];
    o.w = acc[i][3] + bsum[3];
    *reinterpret_cast<float4*>(&G[(size_t)(m0 + ty*4 + i) * 256 + col]) = o;
  }
}

// P[b*Tc+tt] = x[b, t0+tt, :] @ w21 + bias2.  One wave per row, 4 rows/block.
__global__ __launch_bounds__(256) void pz_kernel(const float* __restrict__ X,
                                                 const float* __restrict__ w21,
                                                 const float* __restrict__ bias2,
                                                 float* __restrict__ P,
                                                 int t0, int Tc) {
  const int r = blockIdx.x * 4 + (threadIdx.x >> 6);
  const int lane = threadIdx.x & 63;
  const int bb = r / Tc;
  const int tt = r - bb * Tc;
  const float4 xv = *reinterpret_cast<const float4*>(
      &X[((size_t)(bb * TT + t0 + tt)) * 256 + lane * 4]);
  const float4 wv = *reinterpret_cast<const float4*>(&w21[lane * 4]);
  float s = xv.x*wv.x + xv.y*wv.y + xv.z*wv.z + xv.w*wv.w;
#pragma unroll
  for (int o = 32; o; o >>= 1) s += __shfl_xor(s, o);
  if (lane == 0) P[r] = s + bias2[0];
}

// Serial recurrence: ONE WAVE per batch row. Lane l owns hidden unit l:
// it holds Whh rows {l, 64+l, 128+l, 192+l} in VGPRs (packed float2),
// computes all four gate pre-activations for unit l, and updates c_l/h_l
// locally. No __syncthreads (single-wave WG; same-wave LDS ops are in-order).
// h is broadcast via 1 ds_write + 16 uniform-address ds_read_b128 per step;
// the pz shuffle-butterfly runs on the register copy of h, overlapping the
// LDS write->read latency.
__global__ __launch_bounds__(64, 1) void lstm_seq1(const float* __restrict__ G,
                                                   const float* __restrict__ P,
                                                   const float* __restrict__ Wih,
                                                   const float* __restrict__ Whh,
                                                   const float* __restrict__ w22,
                                                   float* __restrict__ Z,
                                                   float* __restrict__ hq,
                                                   float* __restrict__ cq,
                                                   int t0, int Tc) {
  const int b = blockIdx.x;
  const int l = threadIdx.x;   // 0..63 = hidden unit
  __shared__ __align__(16) float h_s[64];

  // Whh rows for this lane's 4 gates, packed as float2 (v_pk_fma_f32 operands)
  v2f wh0[32], wh1[32], wh2_[32], wh3[32];
#pragma unroll
  for (int j = 0; j < 16; ++j) {
    float4 v0 = *reinterpret_cast<const float4*>(&Whh[(size_t)(0*64 + l)*64 + 4*j]);
    float4 v1 = *reinterpret_cast<const float4*>(&Whh[(size_t)(1*64 + l)*64 + 4*j]);
    float4 v2 = *reinterpret_cast<const float4*>(&Whh[(size_t)(2*64 + l)*64 + 4*j]);
    float4 v3 = *reinterpret_cast<const float4*>(&Whh[(size_t)(3*64 + l)*64 + 4*j]);
    wh0[2*j] = v2f{v0.x, v0.y}; wh0[2*j+1] = v2f{v0.z, v0.w};
    wh1[2*j] = v2f{v1.x, v1.y}; wh1[2*j+1] = v2f{v1.z, v1.w};
    wh2_[2*j] = v2f{v2.x, v2.y}; wh2_[2*j+1] = v2f{v2.z, v2.w};
    wh3[2*j] = v2f{v3.x, v3.y}; wh3[2*j+1] = v2f{v3.z, v3.w};
  }
  const float wihL0 = Wih[(size_t)(0*64 + l)*257 + 256];
  const float wihL1 = Wih[(size_t)(1*64 + l)*257 + 256];
  const float wihL2 = Wih[(size_t)(2*64 + l)*257 + 256];
  const float wihL3 = Wih[(size_t)(3*64 + l)*257 + 256];
  const float w22r = w22[l];

  float h = 0.f, c = 0.f;
  if (t0 != 0) { h = hq[b * 64 + l]; c = cq[b * 64 + l]; }
  h_s[l] = h;
  __builtin_amdgcn_wave_barrier();

  const float* Gb = G + (size_t)b * Tc * 256 + l;
  const float* Pb = P + (size_t)b * Tc;
  float* Zb = Z + (size_t)b * TT + t0;

  float gx0 = Gb[0*64], gx1 = Gb[1*64], gx2 = Gb[2*64], gx3 = Gb[3*64];
  float p0 = Pb[0];

  for (int tt = 0; tt < Tc; ++tt) {
    const int ttn = (tt + 1 < Tc) ? tt + 1 : tt;
    const float* Gn = Gb + (size_t)ttn * 256;
    const float gx0n = Gn[0*64], gx1n = Gn[1*64], gx2n = Gn[2*64], gx3n = Gn[3*64];
    const float p0n = Pb[ttn];

    // pz: full-wave reduction on the register copy of h (overlaps LDS latency)
    float pv = h * w22r;
#pragma unroll
    for (int o = 32; o; o >>= 1) pv += __shfl_xor(pv, o);
    const float pz = fsig(pv + p0);

    // dot(h, Whh[q*64+l, :]) for q=0..3 — h broadcast from LDS, weights in VGPRs
    v2f a00 = v2f{0.f,0.f}, a01 = v2f{0.f,0.f};
    v2f a10 = v2f{0.f,0.f}, a11 = v2f{0.f,0.f};
    v2f a20 = v2f{0.f,0.f}, a21 = v2f{0.f,0.f};
    v2f a30 = v2f{0.f,0.f}, a31 = v2f{0.f,0.f};
#pragma unroll
    for (int jj = 0; jj < 16; ++jj) {
      const float4 hv = *reinterpret_cast<const float4*>(&h_s[4*jj]);
      const v2f h01 = v2f{hv.x, hv.y};
      const v2f h23 = v2f{hv.z, hv.w};
      a00 = fma2(h01, wh0[2*jj], a00);   a01 = fma2(h23, wh0[2*jj+1], a01);
      a10 = fma2(h01, wh1[2*jj], a10);   a11 = fma2(h23, wh1[2*jj+1], a11);
      a20 = fma2(h01, wh2_[2*jj], a20);  a21 = fma2(h23, wh2_[2*jj+1], a21);
      a30 = fma2(h01, wh3[2*jj], a30);   a31 = fma2(h23, wh3[2*jj+1], a31);
    }
    const v2f s0 = a00 + a01, s1 = a10 + a11, s2 = a20 + a21, s3 = a30 + a31;
    const float pre0 = gx0 + pz * wihL0 + (s0.x + s0.y);
    const float pre1 = gx1 + pz * wihL1 + (s1.x + s1.y);
    const float pre2 = gx2 + pz * wihL2 + (s2.x + s2.y);
    const float pre3 = gx3 + pz * wihL3 + (s3.x + s3.y);

    const float ai = fsig(pre0);
    const float af = fsig(pre1);
    const float ag = ftan(pre2);
    const float ao = fsig(pre3);
    c = af * c + ai * ag;
    h = ao * ftan(c);

    if (l == 0) Zb[tt] = pz;

    __builtin_amdgcn_wave_barrier();   // all h_s reads above stay above
    h_s[l] = h;
    __builtin_amdgcn_wave_barrier();   // write stays before next iter's reads

    gx0 = gx0n; gx1 = gx1n; gx2 = gx2n; gx3 = gx3n; p0 = p0n;
  }
  hq[b * 64 + l] = h;
  cq[b * 64 + l] = c;
}

// Fully-inline fallback (only if d_ws is too small for even a 64-step chunk).
__global__ __launch_bounds__(256) void lstm_fallback(const float* __restrict__ X,
    const float* __restrict__ w21, const float* __restrict__ w22,
    const float* __restrict__ bias2, const float* __restrict__ Wih,
    const float* __restrict__ Whh, const float* __restrict__ bih,
    const float* __restrict__ bhh, float* __restrict__ Z) {
  const int b = blockIdx.x;
  const int g = threadIdx.x;
  const int lane = g & 63;
  __shared__ __align__(16) float h_s[64];
  __shared__ float act_s[256];
  __shared__ __align__(16) float x_s[256];
  __shared__ __align__(16) float w21_s[256];
  float wh[64];
#pragma unroll
  for (int j = 0; j < 64; j += 4) {
    float4 v = *reinterpret_cast<const float4*>(&Whh[(size_t)g*64 + j]);
    wh[j]=v.x; wh[j+1]=v.y; wh[j+2]=v.z; wh[j+3]=v.w;
  }
  const float wihL = Wih[(size_t)g*257 + 256];
  const float bias = bih[g] + bhh[g];
  const float b2 = bias2[0];
  const float w22r = w22[lane];
  w21_s[g] = w21[g];
  if (g < 64) h_s[g] = 0.f;
  float c = 0.f;
  __syncthreads();
  const float* Wr = Wih + (size_t)g * 257;
  for (int t = 0; t < TT; ++t) {
    x_s[g] = X[((size_t)b*TT + t)*256 + g];
    __syncthreads();
    float pv = h_s[lane] * w22r;
    {
      const float4 xq = *reinterpret_cast<const float4*>(&x_s[lane*4]);
      const float4 wq = *reinterpret_cast<const float4*>(&w21_s[lane*4]);
      pv += xq.x*wq.x + xq.y*wq.y + xq.z*wq.z + xq.w*wq.w;
    }
#pragma unroll
    for (int o = 32; o; o >>= 1) pv += __shfl_xor(pv, o);
    const float pz = fsig(pv + b2);
    float a0=0.f, a1=0.f, a2=0.f, a3=0.f;
#pragma unroll
    for (int j = 0; j < 64; j += 4) {
      float4 hv = *reinterpret_cast<const float4*>(&h_s[j]);
      a0 += hv.x*wh[j]; a1 += hv.y*wh[j+1]; a2 += hv.z*wh[j+2]; a3 += hv.w*wh[j+3];
    }
    float xd0=0.f, xd1=0.f, xd2=0.f, xd3=0.f;
    for (int k = 0; k < 256; k += 4) {
      const float4 xq = *reinterpret_cast<const float4*>(&x_s[k]);
      xd0 += xq.x*Wr[k]; xd1 += xq.y*Wr[k+1]; xd2 += xq.z*Wr[k+2]; xd3 += xq.w*Wr[k+3];
    }
    const float pre = bias + pz*wihL + ((a0+a1)+(a2+a3)) + ((xd0+xd1)+(xd2+xd3));
    act_s[g] = ((g >> 6) == 2) ? ftan(pre) : fsig(pre);
    if (g == 0) Z[(size_t)b*TT + t] = pz;
    __syncthreads();
    if (g < 64) {
      const float iv = act_s[g], fv = act_s[64+g], gv = act_s[128+g], ov = act_s[192+g];
      c = fv*c + iv*gv;
      h_s[g] = ov * ftan(c);
    }
    __syncthreads();
  }
}

extern "C" void kernel_launch(void* const* d_in, const int* in_sizes, int n_in,
                              void* d_out, int out_size, void* d_ws, size_t ws_size,
                              hipStream_t stream) {
  const float* X     = (const float*)d_in[0];  // [64,2048,256]
  const float* w21   = (const float*)d_in[1];  // [256]
  const float* w22   = (const float*)d_in[2];  // [64]
  const float* bias2 = (const float*)d_in[3];  // [1]
  const float* Wih   = (const float*)d_in[4];  // [256,257]
  const float* Whh   = (const float*)d_in[5];  // [256,64]
  const float* bih   = (const float*)d_in[6];  // [256]
  const float* bhh   = (const float*)d_in[7];  // [256]
  float* Z = (float*)d_out;                    // [64,2048]

  // Pick the largest time-chunk that fits in workspace.
  int Tc = 0;
  for (int cand = 2048; cand >= 64; cand >>= 1) {
    size_t need = (size_t)cand * (64*256*4 + 64*4) + 2*64*64*4;
    if (ws_size >= need) { Tc = cand; break; }
  }
  if (Tc == 0) {
    lstm_fallback<<<dim3(64), dim3(256), 0, stream>>>(X, w21, w22, bias2, Wih, Whh, bih, bhh, Z);
    return;
  }
  float* Gbuf = (float*)d_ws;                       // [64*Tc, 256]
  float* Pbuf = Gbuf + (size_t)64 * Tc * 256;       // [64*Tc]
  float* hq   = Pbuf + (size_t)64 * Tc;             // [64,64]
  float* cq   = hq + 64 * 64;                       // [64,64]
  for (int t0 = 0; t0 < 2048; t0 += Tc) {
    gates_gemm<<<dim3(Tc, 4), dim3(256), 0, stream>>>(X, Wih, bih, bhh, Gbuf, t0, Tc);
    pz_kernel<<<dim3(16 * Tc), dim3(256), 0, stream>>>(X, w21, bias2, Pbuf, t0, Tc);
    lstm_seq1<<<dim3(64), dim3(64), 0, stream>>>(Gbuf, Pbuf, Wih, Whh, w22, Z, hq, cq, t0, Tc);
  }
}

// Round 4
// 1372.486 us; speedup vs baseline: 1.4872x; 1.4872x over previous
//
#include <hip/hip_runtime.h>

#define TT 2048
#define BB 64

typedef float v2f __attribute__((ext_vector_type(2)));

__device__ __forceinline__ float frcp(float x) { return __builtin_amdgcn_rcpf(x); }
__device__ __forceinline__ float fsig(float x) { return frcp(1.f + __expf(-x)); }
__device__ __forceinline__ float ftan(float x) { return 1.f - 2.f * frcp(1.f + __expf(2.f * x)); }
__device__ __forceinline__ v2f fma2(v2f a, v2f b, v2f c) { return __builtin_elementwise_fma(a, b, c); }

// Canonical GCN wave64 sum-reduction via DPP (rocPRIM sequence):
// row_shr:1,2,4,8 accumulate upward within each 16-lane row; row_bcast:15
// then row_bcast:31 merge rows; total lands in lane 63.
#define DPPADD(x, ctrl)                                                        \
  (x) += __builtin_bit_cast(float, __builtin_amdgcn_update_dpp(                \
             0, __builtin_bit_cast(int, (x)), (ctrl), 0xf, 0xf, true))

__device__ __forceinline__ float wave_sum64(float x) {
  DPPADD(x, 0x111);  // row_shr:1
  DPPADD(x, 0x112);  // row_shr:2
  DPPADD(x, 0x114);  // row_shr:4
  DPPADD(x, 0x118);  // row_shr:8
  DPPADD(x, 0x142);  // row_bcast:15
  DPPADD(x, 0x143);  // row_bcast:31
  return __builtin_bit_cast(
      float, __builtin_amdgcn_readlane(__builtin_bit_cast(int, x), 63));
}

// G[(b*Tc+tt)*256 + g] = sum_k X[b, t0+tt, k] * W_ih[g, k] + b_ih[g] + b_hh[g]
// Tiled fp32 GEMM: M = 64*Tc, N = 256, K = 256. grid=(Tc,4), block=256, tile 64x64.
__global__ __launch_bounds__(256) void gates_gemm(const float* __restrict__ X,
                                                  const float* __restrict__ W,
                                                  const float* __restrict__ bih,
                                                  const float* __restrict__ bhh,
                                                  float* __restrict__ G,
                                                  int t0, int Tc) {
  __shared__ __align__(16) float As[32][64];  // As[k][m]
  __shared__ __align__(16) float Bs[32][64];  // Bs[k][n]
  const int tid = threadIdx.x;
  const int m0 = blockIdx.x * 64;
  const int n0 = blockIdx.y * 64;
  const int bb = m0 / Tc;
  const int tt0 = m0 - bb * Tc;
  const int tx = tid & 15, ty = tid >> 4;
  const int r  = tid >> 2;
  const int kq = (tid & 3) * 8;
  const float* xrow = X + ((size_t)(bb * TT + t0 + tt0 + r)) * 256 + kq;
  const float* wrow = W + (size_t)(n0 + r) * 257 + kq;
  float acc[4][4] = {};
  for (int k0 = 0; k0 < 256; k0 += 32) {
    float4 a0 = *reinterpret_cast<const float4*>(xrow + k0);
    float4 a1 = *reinterpret_cast<const float4*>(xrow + k0 + 4);
    float bv[8];
#pragma unroll
    for (int u = 0; u < 8; ++u) bv[u] = wrow[k0 + u];
    if (k0 != 0) __syncthreads();
    As[kq+0][r]=a0.x; As[kq+1][r]=a0.y; As[kq+2][r]=a0.z; As[kq+3][r]=a0.w;
    As[kq+4][r]=a1.x; As[kq+5][r]=a1.y; As[kq+6][r]=a1.z; As[kq+7][r]=a1.w;
#pragma unroll
    for (int u = 0; u < 8; ++u) Bs[kq+u][r] = bv[u];
    __syncthreads();
#pragma unroll
    for (int kk = 0; kk < 32; ++kk) {
      float4 av = *reinterpret_cast<const float4*>(&As[kk][ty*4]);
      float4 bw = *reinterpret_cast<const float4*>(&Bs[kk][tx*4]);
      const float aa[4] = {av.x, av.y, av.z, av.w};
      const float bbv[4] = {bw.x, bw.y, bw.z, bw.w};
#pragma unroll
      for (int i = 0; i < 4; ++i)
#pragma unroll
        for (int j = 0; j < 4; ++j) acc[i][j] += aa[i] * bbv[j];
    }
  }
  const int col = n0 + tx * 4;
  float bsum[4];
#pragma unroll
  for (int j = 0; j < 4; ++j) bsum[j] = bih[col + j] + bhh[col + j];
#pragma unroll
  for (int i = 0; i < 4; ++i) {
    float4 o;
    o.x = acc[i][0] + bsum[0];
    o.y = acc[i][1] + bsum[1];
    o.z = acc[i][2] + bsum[2];
    o.w = acc[i][3] + bsum[3];
    *reinterpret_cast<float4*>(&G[(size_t)(m0 + ty*4 + i) * 256 + col]) = o;
  }
}

// P[b*Tc+tt] = x[b, t0+tt, :] @ w21 + bias2.  One wave per row, 4 rows/block.
__global__ __launch_bounds__(256) void pz_kernel(const float* __restrict__ X,
                                                 const float* __restrict__ w21,
                                                 const float* __restrict__ bias2,
                                                 float* __restrict__ P,
                                                 int t0, int Tc) {
  const int r = blockIdx.x * 4 + (threadIdx.x >> 6);
  const int lane = threadIdx.x & 63;
  const int bb = r / Tc;
  const int tt = r - bb * Tc;
  const float4 xv = *reinterpret_cast<const float4*>(
      &X[((size_t)(bb * TT + t0 + tt)) * 256 + lane * 4]);
  const float4 wv = *reinterpret_cast<const float4*>(&w21[lane * 4]);
  float s = xv.x*wv.x + xv.y*wv.y + xv.z*wv.z + xv.w*wv.w;
#pragma unroll
  for (int o = 32; o; o >>= 1) s += __shfl_xor(s, o);
  if (lane == 0) P[r] = s + bias2[0];
}

// Serial recurrence: TWO waves per batch row; lane l of wave w owns gates
// {w, w+2} of hidden unit l (PyTorch order i,f,g,o). All recurrent math fp32:
// 128 weight VGPRs/lane -> no AGPR spill. Wave0 computes ig = sig(i)*tanh(g);
// wave1 owns c/h: c = sig(f)*c + ig, h = sig(o)*tanh(c). One LDS float (ig)
// crosses waves per step; barriers sit at top level (uniform). pz raw sum
// (h.w22, DPP-reduced by wave1) is computed off the critical path at the end
// of the previous step. G/P register-prefetched 4 steps ahead.
__global__ __launch_bounds__(128, 1) void lstm_seq2(const float* __restrict__ G,
                                                    const float* __restrict__ P,
                                                    const float* __restrict__ Wih,
                                                    const float* __restrict__ Whh,
                                                    const float* __restrict__ w22,
                                                    float* __restrict__ Z,
                                                    float* __restrict__ hq,
                                                    float* __restrict__ cq,
                                                    int t0, int Tc) {
  const int b = blockIdx.x;
  const int tid = threadIdx.x;
  const int w = tid >> 6;     // wave 0: gates (i,g);  wave 1: gates (f,o)
  const int l = tid & 63;     // hidden unit
  __shared__ __align__(16) float h_s[64];
  __shared__ float ig_s[64];
  __shared__ float pzs_s;     // raw h . w22 sum for next step's pz

  // Weights for this lane's two gate rows, packed v2f for v_pk_fma_f32.
  const int rowA = w * 64 + l;        // gate w   (i or f)
  const int rowB = rowA + 128;        // gate w+2 (g or o)
  v2f whA[32], whB[32];
#pragma unroll
  for (int j = 0; j < 16; ++j) {
    float4 va = *reinterpret_cast<const float4*>(&Whh[(size_t)rowA * 64 + 4*j]);
    float4 vb = *reinterpret_cast<const float4*>(&Whh[(size_t)rowB * 64 + 4*j]);
    whA[2*j] = v2f{va.x, va.y}; whA[2*j+1] = v2f{va.z, va.w};
    whB[2*j] = v2f{vb.x, vb.y}; whB[2*j+1] = v2f{vb.z, vb.w};
  }
  const float wihLA = Wih[(size_t)rowA * 257 + 256];
  const float wihLB = Wih[(size_t)rowB * 257 + 256];
  const float w22r  = w22[l];
  // Branchless 2nd activation: wave0 tanh(x)=2*sig(2x)-1 ; wave1 sig(x).
  const float kB = w ? 1.f : 2.f;
  const float mB = w ? 1.f : 2.f;
  const float aB = w ? 0.f : -1.f;

  float h = 0.f, c = 0.f;
  if (t0 != 0) { h = hq[b * 64 + l]; c = cq[b * 64 + l]; }
  if (w == 1) {
    h_s[l] = h;
    const float tot = wave_sum64(h * w22r);
    if (l == 0) pzs_s = tot;
  }
  __syncthreads();

  const float* Gb = G + (size_t)b * Tc * 256;
  const float* Pb = P + (size_t)b * Tc;
  float* Zb = Z + (size_t)b * TT + t0;
  const int offA = w * 64 + l;
  const int offB = offA + 128;

  // Prefetch ring, distance 4 (static indices via full unroll).
  float grA[4], grB[4], pr[4];
#pragma unroll
  for (int u = 0; u < 4; ++u) {
    grA[u] = Gb[(size_t)u * 256 + offA];
    grB[u] = Gb[(size_t)u * 256 + offB];
    pr[u]  = Pb[u];
  }

  for (int tt = 0; tt < Tc; tt += 4) {
    float zs[4];
#pragma unroll
    for (int u = 0; u < 4; ++u) {
      const int step = tt + u;
      const float gxA = grA[u], gxB = grB[u], p0 = pr[u];
      int pf = step + 4; if (pf > Tc - 1) pf = Tc - 1;
      grA[u] = Gb[(size_t)pf * 256 + offA];
      grB[u] = Gb[(size_t)pf * 256 + offB];
      pr[u]  = Pb[pf];

      // pz for this step (raw h.w22 sum produced at end of previous step)
      const float pz = fsig(pzs_s + p0);

      // two 64-wide dots against broadcast h (uniform b128 LDS reads)
      v2f aA0 = v2f{0.f,0.f}, aA1 = v2f{0.f,0.f};
      v2f aB0 = v2f{0.f,0.f}, aB1 = v2f{0.f,0.f};
      const float4* hp = reinterpret_cast<const float4*>(h_s);
#pragma unroll
      for (int jj = 0; jj < 16; ++jj) {
        const float4 hv = hp[jj];
        const v2f h01 = v2f{hv.x, hv.y};
        const v2f h23 = v2f{hv.z, hv.w};
        aA0 = fma2(h01, whA[2*jj],   aA0);
        aA1 = fma2(h23, whA[2*jj+1], aA1);
        aB0 = fma2(h01, whB[2*jj],   aB0);
        aB1 = fma2(h23, whB[2*jj+1], aB1);
      }
      const v2f sA = aA0 + aA1, sB = aB0 + aB1;
      const float preA = gxA + pz * wihLA + (sA.x + sA.y);
      const float preB = gxB + pz * wihLB + (sB.x + sB.y);
      const float actA = fsig(preA);                 // sig(i) / sig(f)
      const float actB = mB * fsig(kB * preB) + aB;  // tanh(g) / sig(o)

      if (w == 0) ig_s[l] = actA * actB;             // sig(i)*tanh(g)
      __syncthreads();                               // B1: ig ready
      if (w == 1) {
        c = actA * c + ig_s[l];                      // sig(f)*c + ig
        h = actB * ftan(c);                          // sig(o)*tanh(c)
        h_s[l] = h;
        const float tot = wave_sum64(h * w22r);      // next step's pz raw sum
        if (l == 0) pzs_s = tot;
      }
      zs[u] = pz;
      __syncthreads();                               // B2: h/pzs ready
    }
    if (w == 1 && l == 0) {
      float4 zo; zo.x = zs[0]; zo.y = zs[1]; zo.z = zs[2]; zo.w = zs[3];
      *reinterpret_cast<float4*>(&Zb[tt]) = zo;
    }
  }
  if (w == 1) { hq[b * 64 + l] = h; cq[b * 64 + l] = c; }
}

// Fully-inline fp32 fallback (only if d_ws is too small for a 64-step chunk).
__global__ __launch_bounds__(256) void lstm_fallback(const float* __restrict__ X,
    const float* __restrict__ w21, const float* __restrict__ w22,
    const float* __restrict__ bias2, const float* __restrict__ Wih,
    const float* __restrict__ Whh, const float* __restrict__ bih,
    const float* __restrict__ bhh, float* __restrict__ Z) {
  const int b = blockIdx.x;
  const int g = threadIdx.x;
  const int lane = g & 63;
  __shared__ __align__(16) float h_s[64];
  __shared__ float act_s[256];
  __shared__ __align__(16) float x_s[256];
  __shared__ __align__(16) float w21_s[256];
  float wh[64];
#pragma unroll
  for (int j = 0; j < 64; j += 4) {
    float4 v = *reinterpret_cast<const float4*>(&Whh[(size_t)g*64 + j]);
    wh[j]=v.x; wh[j+1]=v.y; wh[j+2]=v.z; wh[j+3]=v.w;
  }
  const float wihL = Wih[(size_t)g*257 + 256];
  const float bias = bih[g] + bhh[g];
  const float b2 = bias2[0];
  const float w22r = w22[lane];
  w21_s[g] = w21[g];
  if (g < 64) h_s[g] = 0.f;
  float c = 0.f;
  __syncthreads();
  const float* Wr = Wih + (size_t)g * 257;
  for (int t = 0; t < TT; ++t) {
    x_s[g] = X[((size_t)b*TT + t)*256 + g];
    __syncthreads();
    float pv = h_s[lane] * w22r;
    {
      const float4 xq = *reinterpret_cast<const float4*>(&x_s[lane*4]);
      const float4 wq = *reinterpret_cast<const float4*>(&w21_s[lane*4]);
      pv += xq.x*wq.x + xq.y*wq.y + xq.z*wq.z + xq.w*wq.w;
    }
#pragma unroll
    for (int o = 32; o; o >>= 1) pv += __shfl_xor(pv, o);
    const float pz = fsig(pv + b2);
    float a0=0.f, a1=0.f, a2=0.f, a3=0.f;
#pragma unroll
    for (int j = 0; j < 64; j += 4) {
      float4 hv = *reinterpret_cast<const float4*>(&h_s[j]);
      a0 += hv.x*wh[j]; a1 += hv.y*wh[j+1]; a2 += hv.z*wh[j+2]; a3 += hv.w*wh[j+3];
    }
    float xd0=0.f, xd1=0.f, xd2=0.f, xd3=0.f;
    for (int k = 0; k < 256; k += 4) {
      const float4 xq = *reinterpret_cast<const float4*>(&x_s[k]);
      xd0 += xq.x*Wr[k]; xd1 += xq.y*Wr[k+1]; xd2 += xq.z*Wr[k+2]; xd3 += xq.w*Wr[k+3];
    }
    const float pre = bias + pz*wihL + ((a0+a1)+(a2+a3)) + ((xd0+xd1)+(xd2+xd3));
    act_s[g] = ((g >> 6) == 2) ? ftan(pre) : fsig(pre);
    if (g == 0) Z[(size_t)b*TT + t] = pz;
    __syncthreads();
    if (g < 64) {
      const float iv = act_s[g], fv = act_s[64+g], gv = act_s[128+g], ov = act_s[192+g];
      c = fv*c + iv*gv;
      h_s[g] = ov * ftan(c);
    }
    __syncthreads();
  }
}

extern "C" void kernel_launch(void* const* d_in, const int* in_sizes, int n_in,
                              void* d_out, int out_size, void* d_ws, size_t ws_size,
                              hipStream_t stream) {
  const float* X     = (const float*)d_in[0];  // [64,2048,256]
  const float* w21   = (const float*)d_in[1];  // [256]
  const float* w22   = (const float*)d_in[2];  // [64]
  const float* bias2 = (const float*)d_in[3];  // [1]
  const float* Wih   = (const float*)d_in[4];  // [256,257]
  const float* Whh   = (const float*)d_in[5];  // [256,64]
  const float* bih   = (const float*)d_in[6];  // [256]
  const float* bhh   = (const float*)d_in[7];  // [256]
  float* Z = (float*)d_out;                    // [64,2048]

  int Tc = 0;
  for (int cand = 2048; cand >= 64; cand >>= 1) {
    size_t need = (size_t)cand * (64*256*4 + 64*4) + 2*64*64*4;
    if (ws_size >= need) { Tc = cand; break; }
  }
  if (Tc == 0) {
    lstm_fallback<<<dim3(64), dim3(256), 0, stream>>>(X, w21, w22, bias2, Wih, Whh, bih, bhh, Z);
    return;
  }
  float* Gbuf = (float*)d_ws;                       // [64*Tc, 256]
  float* Pbuf = Gbuf + (size_t)64 * Tc * 256;       // [64*Tc]
  float* hq   = Pbuf + (size_t)64 * Tc;             // [64,64]
  float* cq   = hq + 64 * 64;                       // [64,64]
  for (int t0 = 0; t0 < 2048; t0 += Tc) {
    gates_gemm<<<dim3(Tc, 4), dim3(256), 0, stream>>>(X, Wih, bih, bhh, Gbuf, t0, Tc);
    pz_kernel<<<dim3(16 * Tc), dim3(256), 0, stream>>>(X, w21, bias2, Pbuf, t0, Tc);
    lstm_seq2<<<dim3(64), dim3(128), 0, stream>>>(Gbuf, Pbuf, Wih, Whh, w22, Z, hq, cq, t0, Tc);
  }
}

// Round 5
// 1228.972 us; speedup vs baseline: 1.6609x; 1.1168x over previous
//
#include <hip/hip_runtime.h>

#define TT 2048
#define BB 64

typedef float v2f __attribute__((ext_vector_type(2)));

__device__ __forceinline__ float frcp(float x) { return __builtin_amdgcn_rcpf(x); }
__device__ __forceinline__ float fsig(float x) { return frcp(1.f + __expf(-x)); }
__device__ __forceinline__ float ftan(float x) { return 1.f - 2.f * frcp(1.f + __expf(2.f * x)); }
__device__ __forceinline__ v2f fma2(v2f a, v2f b, v2f c) { return __builtin_elementwise_fma(a, b, c); }

// Raw barrier: LDS ordering only. Does NOT drain vmcnt -> global prefetch
// loads stay in flight across the barrier (the __syncthreads() vmcnt(0)
// drain was the R4 bottleneck: it serialized the G-load latency every step).
__device__ __forceinline__ void barrier_lgkm() {
  asm volatile("s_waitcnt lgkmcnt(0)\n\ts_barrier" ::: "memory");
}

// Canonical GCN wave64 sum-reduction via DPP (verified in R4):
// row_shr:1,2,4,8 then row_bcast:15, row_bcast:31; total lands in lane 63.
#define DPPADD(x, ctrl)                                                        \
  (x) += __builtin_bit_cast(float, __builtin_amdgcn_update_dpp(                \
             0, __builtin_bit_cast(int, (x)), (ctrl), 0xf, 0xf, true))

__device__ __forceinline__ float wave_sum64(float x) {
  DPPADD(x, 0x111);  // row_shr:1
  DPPADD(x, 0x112);  // row_shr:2
  DPPADD(x, 0x114);  // row_shr:4
  DPPADD(x, 0x118);  // row_shr:8
  DPPADD(x, 0x142);  // row_bcast:15
  DPPADD(x, 0x143);  // row_bcast:31
  return __builtin_bit_cast(
      float, __builtin_amdgcn_readlane(__builtin_bit_cast(int, x), 63));
}

// G[(b*Tc+tt)*256 + g] = sum_k X[b, t0+tt, k] * W_ih[g, k] + b_ih[g] + b_hh[g]
// Tiled fp32 GEMM: M = 64*Tc, N = 256, K = 256. grid=(Tc,4), block=256, tile 64x64.
__global__ __launch_bounds__(256) void gates_gemm(const float* __restrict__ X,
                                                  const float* __restrict__ W,
                                                  const float* __restrict__ bih,
                                                  const float* __restrict__ bhh,
                                                  float* __restrict__ G,
                                                  int t0, int Tc) {
  __shared__ __align__(16) float As[32][64];  // As[k][m]
  __shared__ __align__(16) float Bs[32][64];  // Bs[k][n]
  const int tid = threadIdx.x;
  const int m0 = blockIdx.x * 64;
  const int n0 = blockIdx.y * 64;
  const int bb = m0 / Tc;
  const int tt0 = m0 - bb * Tc;
  const int tx = tid & 15, ty = tid >> 4;
  const int r  = tid >> 2;
  const int kq = (tid & 3) * 8;
  const float* xrow = X + ((size_t)(bb * TT + t0 + tt0 + r)) * 256 + kq;
  const float* wrow = W + (size_t)(n0 + r) * 257 + kq;
  float acc[4][4] = {};
  for (int k0 = 0; k0 < 256; k0 += 32) {
    float4 a0 = *reinterpret_cast<const float4*>(xrow + k0);
    float4 a1 = *reinterpret_cast<const float4*>(xrow + k0 + 4);
    float bv[8];
#pragma unroll
    for (int u = 0; u < 8; ++u) bv[u] = wrow[k0 + u];
    if (k0 != 0) __syncthreads();
    As[kq+0][r]=a0.x; As[kq+1][r]=a0.y; As[kq+2][r]=a0.z; As[kq+3][r]=a0.w;
    As[kq+4][r]=a1.x; As[kq+5][r]=a1.y; As[kq+6][r]=a1.z; As[kq+7][r]=a1.w;
#pragma unroll
    for (int u = 0; u < 8; ++u) Bs[kq+u][r] = bv[u];
    __syncthreads();
#pragma unroll
    for (int kk = 0; kk < 32; ++kk) {
      float4 av = *reinterpret_cast<const float4*>(&As[kk][ty*4]);
      float4 bw = *reinterpret_cast<const float4*>(&Bs[kk][tx*4]);
      const float aa[4] = {av.x, av.y, av.z, av.w};
      const float bbv[4] = {bw.x, bw.y, bw.z, bw.w};
#pragma unroll
      for (int i = 0; i < 4; ++i)
#pragma unroll
        for (int j = 0; j < 4; ++j) acc[i][j] += aa[i] * bbv[j];
    }
  }
  const int col = n0 + tx * 4;
  float bsum[4];
#pragma unroll
  for (int j = 0; j < 4; ++j) bsum[j] = bih[col + j] + bhh[col + j];
#pragma unroll
  for (int i = 0; i < 4; ++i) {
    float4 o;
    o.x = acc[i][0] + bsum[0];
    o.y = acc[i][1] + bsum[1];
    o.z = acc[i][2] + bsum[2];
    o.w = acc[i][3] + bsum[3];
    *reinterpret_cast<float4*>(&G[(size_t)(m0 + ty*4 + i) * 256 + col]) = o;
  }
}

// P[b*Tc+tt] = x[b, t0+tt, :] @ w21 + bias2.  One wave per row, 4 rows/block.
__global__ __launch_bounds__(256) void pz_kernel(const float* __restrict__ X,
                                                 const float* __restrict__ w21,
                                                 const float* __restrict__ bias2,
                                                 float* __restrict__ P,
                                                 int t0, int Tc) {
  const int r = blockIdx.x * 4 + (threadIdx.x >> 6);
  const int lane = threadIdx.x & 63;
  const int bb = r / Tc;
  const int tt = r - bb * Tc;
  const float4 xv = *reinterpret_cast<const float4*>(
      &X[((size_t)(bb * TT + t0 + tt)) * 256 + lane * 4]);
  const float4 wv = *reinterpret_cast<const float4*>(&w21[lane * 4]);
  float s = xv.x*wv.x + xv.y*wv.y + xv.z*wv.z + xv.w*wv.w;
#pragma unroll
  for (int o = 32; o; o >>= 1) s += __shfl_xor(s, o);
  if (lane == 0) P[r] = s + bias2[0];
}

// Serial recurrence, ONE raw barrier per step:
//   wave w owns hidden units u = w*32 + (l&31).
//   lanes 0-31 (sub=0): gates (i,g) of unit u;  lanes 32-63 (sub=1): (f,o).
//   ig crosses lanes via __shfl_xor(.,32) (intra-wave, no LDS).
//   h crosses waves via ping-pong h_s[2][64] (no write-after-read hazard).
//   pz raw sum computed redundantly per wave (bit-identical DPP sequence).
//   Barriers are raw s_barrier + lgkmcnt(0) only -> G prefetch ring (dist 4)
//   stays in flight across barriers.
__global__ __launch_bounds__(128, 1) void lstm_seq3(const float* __restrict__ G,
                                                    const float* __restrict__ P,
                                                    const float* __restrict__ Wih,
                                                    const float* __restrict__ Whh,
                                                    const float* __restrict__ w22,
                                                    float* __restrict__ Z,
                                                    float* __restrict__ hq,
                                                    float* __restrict__ cq,
                                                    int t0, int Tc) {
  const int b = blockIdx.x;
  const int tid = threadIdx.x;
  const int w = tid >> 6;      // wave: owns units w*32..w*32+31
  const int l = tid & 63;
  const int sub = l >> 5;      // 0: gates (i,g);  1: gates (f,o)
  const int u = w * 32 + (l & 31);   // owned hidden unit
  __shared__ __align__(16) float h_s[2][64];

  // PyTorch gate-row order: i=0..63, f=64..127, g=128..191, o=192..255
  const int rowA = sub * 64 + u;     // i (sub0) or f (sub1)
  const int rowB = rowA + 128;       // g (sub0) or o (sub1)
  v2f whA[32], whB[32];
#pragma unroll
  for (int j = 0; j < 16; ++j) {
    float4 va = *reinterpret_cast<const float4*>(&Whh[(size_t)rowA * 64 + 4*j]);
    float4 vb = *reinterpret_cast<const float4*>(&Whh[(size_t)rowB * 64 + 4*j]);
    whA[2*j] = v2f{va.x, va.y}; whA[2*j+1] = v2f{va.z, va.w};
    whB[2*j] = v2f{vb.x, vb.y}; whB[2*j+1] = v2f{vb.z, vb.w};
  }
  const float wihLA = Wih[(size_t)rowA * 257 + 256];
  const float wihLB = Wih[(size_t)rowB * 257 + 256];
  const float w22r  = w22[l];
  // Branchless B-gate activation: sub0 tanh(x)=2*sig(2x)-1; sub1 sig(x).
  const float kB = sub ? 1.f : 2.f;
  const float mB = sub ? 1.f : 2.f;
  const float aB = sub ? 0.f : -1.f;

  float h = 0.f, c = 0.f;
  if (t0 != 0) { h = hq[b * 64 + u]; c = cq[b * 64 + u]; }
  if (l >= 32) h_s[0][u] = h;    // sub1 lanes of both waves cover u=0..63
  barrier_lgkm();

  const float* Gb = G + (size_t)b * Tc * 256;
  const float* Pb = P + (size_t)b * Tc;
  float* Zb = Z + (size_t)b * TT + t0;

  // Prefetch ring, distance 4 (static indices via full unroll).
  float grA[4], grB[4], pr[4];
#pragma unroll
  for (int q = 0; q < 4; ++q) {
    grA[q] = Gb[(size_t)q * 256 + rowA];
    grB[q] = Gb[(size_t)q * 256 + rowB];
    pr[q]  = Pb[q];
  }

  for (int tt = 0; tt < Tc; tt += 4) {
    float zs[4];
#pragma unroll
    for (int uu = 0; uu < 4; ++uu) {
      const int step = tt + uu;
      const int rb = uu & 1;                 // read-buffer parity (Tc%8==0)
      const float gxA = grA[uu], gxB = grB[uu], p0 = pr[uu];
      int pf = step + 4; if (pf > Tc - 1) pf = Tc - 1;
      grA[uu] = Gb[(size_t)pf * 256 + rowA];
      grB[uu] = Gb[(size_t)pf * 256 + rowB];
      pr[uu]  = Pb[pf];

      // pz raw sum: off critical path, redundant per wave, bit-identical
      float rsum = h_s[rb][l] * w22r;
      const float tot = wave_sum64(rsum);
      const float pz = fsig(tot + p0);

      // two 64-wide dots against broadcast h(t-1); 8-deep fma chains
      v2f aA0{0.f,0.f}, aA1{0.f,0.f}, aA2{0.f,0.f}, aA3{0.f,0.f};
      v2f aB0{0.f,0.f}, aB1{0.f,0.f}, aB2{0.f,0.f}, aB3{0.f,0.f};
      const float4* hp = reinterpret_cast<const float4*>(h_s[rb]);
#pragma unroll
      for (int q = 0; q < 16; q += 2) {
        const float4 hv0 = hp[q];
        const float4 hv1 = hp[q+1];
        const v2f h01 = v2f{hv0.x, hv0.y}, h23 = v2f{hv0.z, hv0.w};
        const v2f h45 = v2f{hv1.x, hv1.y}, h67 = v2f{hv1.z, hv1.w};
        aA0 = fma2(h01, whA[2*q],   aA0);  aA1 = fma2(h23, whA[2*q+1], aA1);
        aA2 = fma2(h45, whA[2*q+2], aA2);  aA3 = fma2(h67, whA[2*q+3], aA3);
        aB0 = fma2(h01, whB[2*q],   aB0);  aB1 = fma2(h23, whB[2*q+1], aB1);
        aB2 = fma2(h45, whB[2*q+2], aB2);  aB3 = fma2(h67, whB[2*q+3], aB3);
      }
      const v2f sA = (aA0 + aA1) + (aA2 + aA3);
      const v2f sB = (aB0 + aB1) + (aB2 + aB3);
      const float preA = gxA + pz * wihLA + (sA.x + sA.y);
      const float preB = gxB + pz * wihLB + (sB.x + sB.y);
      const float actA = fsig(preA);                 // sig(i) / sig(f)
      const float actB = mB * fsig(kB * preB) + aB;  // tanh(g) / sig(o)

      const float prod = actA * actB;                // sub0: ig ; sub1: unused
      const float igx = __shfl_xor(prod, 32);        // sub1 lanes receive ig
      c = actA * c + igx;                            // meaningful on sub1
      h = actB * ftan(c);                            // meaningful on sub1
      if (l >= 32) h_s[rb ^ 1][u] = h;
      zs[uu] = pz;
      barrier_lgkm();
    }
    if (tid == 0) {
      float4 zo; zo.x = zs[0]; zo.y = zs[1]; zo.z = zs[2]; zo.w = zs[3];
      *reinterpret_cast<float4*>(&Zb[tt]) = zo;
    }
  }
  if (l >= 32) { hq[b * 64 + u] = h; cq[b * 64 + u] = c; }
}

// Fully-inline fp32 fallback (only if d_ws is too small for a 64-step chunk).
__global__ __launch_bounds__(256) void lstm_fallback(const float* __restrict__ X,
    const float* __restrict__ w21, const float* __restrict__ w22,
    const float* __restrict__ bias2, const float* __restrict__ Wih,
    const float* __restrict__ Whh, const float* __restrict__ bih,
    const float* __restrict__ bhh, float* __restrict__ Z) {
  const int b = blockIdx.x;
  const int g = threadIdx.x;
  const int lane = g & 63;
  __shared__ __align__(16) float h_s[64];
  __shared__ float act_s[256];
  __shared__ __align__(16) float x_s[256];
  __shared__ __align__(16) float w21_s[256];
  float wh[64];
#pragma unroll
  for (int j = 0; j < 64; j += 4) {
    float4 v = *reinterpret_cast<const float4*>(&Whh[(size_t)g*64 + j]);
    wh[j]=v.x; wh[j+1]=v.y; wh[j+2]=v.z; wh[j+3]=v.w;
  }
  const float wihL = Wih[(size_t)g*257 + 256];
  const float bias = bih[g] + bhh[g];
  const float b2 = bias2[0];
  const float w22r = w22[lane];
  w21_s[g] = w21[g];
  if (g < 64) h_s[g] = 0.f;
  float c = 0.f;
  __syncthreads();
  const float* Wr = Wih + (size_t)g * 257;
  for (int t = 0; t < TT; ++t) {
    x_s[g] = X[((size_t)b*TT + t)*256 + g];
    __syncthreads();
    float pv = h_s[lane] * w22r;
    {
      const float4 xq = *reinterpret_cast<const float4*>(&x_s[lane*4]);
      const float4 wq = *reinterpret_cast<const float4*>(&w21_s[lane*4]);
      pv += xq.x*wq.x + xq.y*wq.y + xq.z*wq.z + xq.w*wq.w;
    }
#pragma unroll
    for (int o = 32; o; o >>= 1) pv += __shfl_xor(pv, o);
    const float pz = fsig(pv + b2);
    float a0=0.f, a1=0.f, a2=0.f, a3=0.f;
#pragma unroll
    for (int j = 0; j < 64; j += 4) {
      float4 hv = *reinterpret_cast<const float4*>(&h_s[j]);
      a0 += hv.x*wh[j]; a1 += hv.y*wh[j+1]; a2 += hv.z*wh[j+2]; a3 += hv.w*wh[j+3];
    }
    float xd0=0.f, xd1=0.f, xd2=0.f, xd3=0.f;
    for (int k = 0; k < 256; k += 4) {
      const float4 xq = *reinterpret_cast<const float4*>(&x_s[k]);
      xd0 += xq.x*Wr[k]; xd1 += xq.y*Wr[k+1]; xd2 += xq.z*Wr[k+2]; xd3 += xq.w*Wr[k+3];
    }
    const float pre = bias + pz*wihL + ((a0+a1)+(a2+a3)) + ((xd0+xd1)+(xd2+xd3));
    act_s[g] = ((g >> 6) == 2) ? ftan(pre) : fsig(pre);
    if (g == 0) Z[(size_t)b*TT + t] = pz;
    __syncthreads();
    if (g < 64) {
      const float iv = act_s[g], fv = act_s[64+g], gv = act_s[128+g], ov = act_s[192+g];
      c = fv*c + iv*gv;
      h_s[g] = ov * ftan(c);
    }
    __syncthreads();
  }
}

extern "C" void kernel_launch(void* const* d_in, const int* in_sizes, int n_in,
                              void* d_out, int out_size, void* d_ws, size_t ws_size,
                              hipStream_t stream) {
  const float* X     = (const float*)d_in[0];  // [64,2048,256]
  const float* w21   = (const float*)d_in[1];  // [256]
  const float* w22   = (const float*)d_in[2];  // [64]
  const float* bias2 = (const float*)d_in[3];  // [1]
  const float* Wih   = (const float*)d_in[4];  // [256,257]
  const float* Whh   = (const float*)d_in[5];  // [256,64]
  const float* bih   = (const float*)d_in[6];  // [256]
  const float* bhh   = (const float*)d_in[7];  // [256]
  float* Z = (float*)d_out;                    // [64,2048]

  int Tc = 0;
  for (int cand = 2048; cand >= 64; cand >>= 1) {
    size_t need = (size_t)cand * (64*256*4 + 64*4) + 2*64*64*4;
    if (ws_size >= need) { Tc = cand; break; }
  }
  if (Tc == 0) {
    lstm_fallback<<<dim3(64), dim3(256), 0, stream>>>(X, w21, w22, bias2, Wih, Whh, bih, bhh, Z);
    return;
  }
  float* Gbuf = (float*)d_ws;                       // [64*Tc, 256]
  float* Pbuf = Gbuf + (size_t)64 * Tc * 256;       // [64*Tc]
  float* hq   = Pbuf + (size_t)64 * Tc;             // [64,64]
  float* cq   = hq + 64 * 64;                       // [64,64]
  for (int t0 = 0; t0 < 2048; t0 += Tc) {
    gates_gemm<<<dim3(Tc, 4), dim3(256), 0, stream>>>(X, Wih, bih, bhh, Gbuf, t0, Tc);
    pz_kernel<<<dim3(16 * Tc), dim3(256), 0, stream>>>(X, w21, bias2, Pbuf, t0, Tc);
    lstm_seq3<<<dim3(64), dim3(128), 0, stream>>>(Gbuf, Pbuf, Wih, Whh, w22, Z, hq, cq, t0, Tc);
  }
}